// Round 1
// baseline (74.572 us; speedup 1.0000x reference)
//
#include <hip/hip_runtime.h>

// Problem constants (match reference): R rules, A antecedents, B samples.
#define RR 32
#define AA 16
#define BLOCK 256

// Precomputed parameter layout in d_ws, per rule r (64-float stride, 256B aligned
// for s_load_dwordx16 friendliness):
//   P[r*64 +  0 .. 15] = a_k  = -0.5/sigma^2 * log2(e)
//   P[r*64 + 16 .. 31] = b_k  =  c/sigma^2   * log2(e)
//   P[r*64 + 32 .. 47] = Cw_k =  C[r][1+k]
//   P[r*64 + 48]       = bias =  C[r][0]
//   P[r*64 + 49]       = K_r  =  sum_k(-0.5 c^2/sigma^2) * log2(e)
//   P[r*64 + 50 .. 63] = unused (re-poisoned by harness each call; never read)

__global__ __launch_bounds__(512) void tsk_precompute(
    const float* __restrict__ W,   // FRB_W, 2*R*A floats (only first 513 used)
    const float* __restrict__ C,   // [R, A+1] row-major
    float* __restrict__ P)
{
    __shared__ float cpart[RR * AA];
    const float LOG2E = 1.4426950408889634f;
    int t = threadIdx.x;  // 512 threads, one block
    if (t < RR * AA) {
        int r = t >> 4, k = t & 15;
        // Faithful to reference indexing: sigma = W[A*r+k], center = W[A*r+k+1]
        float sig = W[t];
        float c   = W[t + 1];
        float inv2 = 1.0f / (sig * sig);
        P[r * 64 + k]      = -0.5f * inv2 * LOG2E;        // a
        P[r * 64 + 16 + k] = c * inv2 * LOG2E;            // b
        cpart[t]           = -0.5f * c * c * inv2 * LOG2E;
        // consequent weights: C[r][1+k]
        P[r * 64 + 32 + k] = C[r * (AA + 1) + 1 + k];
    }
    __syncthreads();
    if (t < RR) {
        float s = 0.0f;
        #pragma unroll
        for (int k = 0; k < AA; ++k) s += cpart[t * AA + k];
        P[t * 64 + 49] = s;                               // K_r
        P[t * 64 + 48] = C[t * (AA + 1)];                 // bias
    }
}

// One thread per sample. Weights read with wave-uniform indices -> scalar loads.
// __launch_bounds__(256,1): only 1024 waves exist grid-wide (1/SIMD), so let the
// register allocator use the full budget rather than throttle for occupancy.
__global__ __launch_bounds__(BLOCK, 1) void tsk_main(
    const float* __restrict__ x,   // [B, A] row-major
    const float* __restrict__ P,   // precomputed params
    float* __restrict__ out,       // [B]
    int B)
{
    int b = blockIdx.x * BLOCK + threadIdx.x;
    if (b >= B) return;

    const float4* xr = (const float4*)(x + (size_t)b * AA);
    float4 v0 = xr[0], v1 = xr[1], v2 = xr[2], v3 = xr[3];
    float xv[AA] = { v0.x, v0.y, v0.z, v0.w,
                     v1.x, v1.y, v1.z, v1.w,
                     v2.x, v2.y, v2.z, v2.w,
                     v3.x, v3.y, v3.z, v3.w };
    float x2[AA];
    #pragma unroll
    for (int k = 0; k < AA; ++k) x2[k] = xv[k] * xv[k];

    float num = 0.0f, den = 0.0f;
    #pragma unroll 2
    for (int r = 0; r < RR; ++r) {
        const float* p = P + r * 64;
        float ea = 0.0f, eb = 0.0f;
        float ch = p[48];
        #pragma unroll
        for (int k = 0; k < AA; ++k) {
            ea = fmaf(p[k],      x2[k], ea);   // sum a*x^2
            eb = fmaf(p[16 + k], xv[k], eb);   // sum b*x
            ch = fmaf(p[32 + k], xv[k], ch);   // consequent dot
        }
        float w = exp2f(ea + eb + p[49]);      // log2e already folded in
        num = fmaf(w, ch, num);
        den += w;
    }
    out[b] = num / den;
}

extern "C" void kernel_launch(void* const* d_in, const int* in_sizes, int n_in,
                              void* d_out, int out_size, void* d_ws, size_t ws_size,
                              hipStream_t stream) {
    const float* x = (const float*)d_in[0];   // input_data [B, A]
    const float* W = (const float*)d_in[1];   // FRB_W [2*R*A]
    const float* C = (const float*)d_in[2];   // C [R, A+1]
    float* out = (float*)d_out;
    float* P = (float*)d_ws;                  // 32*64*4 = 8 KB scratch
    int B = in_sizes[0] / AA;

    tsk_precompute<<<dim3(1), dim3(512), 0, stream>>>(W, C, P);
    tsk_main<<<dim3((B + BLOCK - 1) / BLOCK), dim3(BLOCK), 0, stream>>>(x, P, out, B);
}

// Round 2
// 63.349 us; speedup vs baseline: 1.1772x; 1.1772x over previous
//
#include <hip/hip_runtime.h>

// Problem constants (match reference): R rules, A antecedents, B samples.
#define RR 32
#define AA 16
#define SPLIT 4                 // rule-quarters, one per wave of the block
#define RPW (RR / SPLIT)        // 8 rules per wave
#define BLOCK 256               // 4 waves
#define SPB 64                  // samples per block (one per lane)

// Precomputed parameter layout in d_ws, per rule r (64-float stride):
//   P[r*64 +  0 .. 15] = a_k  = -0.5/sigma^2 * log2(e)
//   P[r*64 + 16 .. 31] = b_k  =  c/sigma^2   * log2(e)
//   P[r*64 + 32 .. 47] = Cw_k =  C[r][1+k]
//   P[r*64 + 48]       = bias =  C[r][0]
//   P[r*64 + 49]       = K_r  =  sum_k(-0.5 c^2/sigma^2) * log2(e)

__global__ __launch_bounds__(512) void tsk_precompute(
    const float* __restrict__ W,   // FRB_W, 2*R*A floats
    const float* __restrict__ C,   // [R, A+1] row-major
    float* __restrict__ P)
{
    __shared__ float cpart[RR * AA];
    const float LOG2E = 1.4426950408889634f;
    int t = threadIdx.x;  // 512 threads, one block
    if (t < RR * AA) {
        int r = t >> 4, k = t & 15;
        // Faithful to reference indexing: sigma = W[A*r+k], center = W[A*r+k+1]
        float sig = W[t];
        float c   = W[t + 1];
        float inv2 = 1.0f / (sig * sig);
        P[r * 64 + k]      = -0.5f * inv2 * LOG2E;        // a
        P[r * 64 + 16 + k] = c * inv2 * LOG2E;            // b
        cpart[t]           = -0.5f * c * c * inv2 * LOG2E;
        P[r * 64 + 32 + k] = C[r * (AA + 1) + 1 + k];     // consequent weight
    }
    __syncthreads();
    if (t < RR) {
        float s = 0.0f;
        #pragma unroll
        for (int k = 0; k < AA; ++k) s += cpart[t * AA + k];
        P[t * 64 + 49] = s;                               // K_r
        P[t * 64 + 48] = C[t * (AA + 1)];                 // bias
    }
}

// Block = 4 waves; each wave handles the SAME 64 samples but a DIFFERENT
// 8-rule quarter (wave-uniform -> weight reads stay on the scalar pipe).
// Partials combined through a tiny LDS reduction.
// NOTE: no early return anywhere before the weight loads — keeps them
// uniformly-reached so LLVM can promote to s_load.
__global__ __launch_bounds__(BLOCK, 4) void tsk_main(
    const float* __restrict__ x,   // [B, A] row-major
    const float* __restrict__ P,   // precomputed params (64 floats/rule)
    float* __restrict__ out,       // [B]
    int B)
{
    __shared__ float pnum[SPLIT][SPB];
    __shared__ float pden[SPLIT][SPB];

    const int lane = threadIdx.x & 63;
    // Force wave-uniformity into an SGPR so the P addresses are provably scalar.
    const int wv = __builtin_amdgcn_readfirstlane(threadIdx.x >> 6);  // 0..3

    int s = blockIdx.x * SPB + lane;
    int sl = s < B ? s : B - 1;   // clamp (no early return)

    const float4* xr = (const float4*)(x + (size_t)sl * AA);
    float4 v0 = xr[0], v1 = xr[1], v2 = xr[2], v3 = xr[3];
    float xv[AA] = { v0.x, v0.y, v0.z, v0.w,
                     v1.x, v1.y, v1.z, v1.w,
                     v2.x, v2.y, v2.z, v2.w,
                     v3.x, v3.y, v3.z, v3.w };
    float x2[AA];
    #pragma unroll
    for (int k = 0; k < AA; ++k) x2[k] = xv[k] * xv[k];

    float num = 0.0f, den = 0.0f;
    const float* pw = P + wv * RPW * 64;   // wave-uniform base
    #pragma unroll 2
    for (int r = 0; r < RPW; ++r) {
        const float* p = pw + r * 64;
        float ea = 0.0f, eb = 0.0f;
        float ch = p[48];
        #pragma unroll
        for (int k = 0; k < AA; ++k) {
            ea = fmaf(p[k],      x2[k], ea);   // sum a*x^2   (SGPR coeff)
            eb = fmaf(p[16 + k], xv[k], eb);   // sum b*x
            ch = fmaf(p[32 + k], xv[k], ch);   // consequent dot
        }
        float w = __builtin_amdgcn_exp2f(ea + eb + p[49]);  // log2e folded in
        num = fmaf(w, ch, num);
        den += w;
    }

    pnum[wv][lane] = num;
    pden[wv][lane] = den;
    __syncthreads();

    if (threadIdx.x < SPB) {
        int t = threadIdx.x;
        float n = pnum[0][t] + pnum[1][t] + pnum[2][t] + pnum[3][t];
        float d = pden[0][t] + pden[1][t] + pden[2][t] + pden[3][t];
        int so = blockIdx.x * SPB + t;
        if (so < B) out[so] = n * __builtin_amdgcn_rcpf(d);
    }
}

extern "C" void kernel_launch(void* const* d_in, const int* in_sizes, int n_in,
                              void* d_out, int out_size, void* d_ws, size_t ws_size,
                              hipStream_t stream) {
    const float* x = (const float*)d_in[0];   // input_data [B, A]
    const float* W = (const float*)d_in[1];   // FRB_W [2*R*A]
    const float* C = (const float*)d_in[2];   // C [R, A+1]
    float* out = (float*)d_out;
    float* P = (float*)d_ws;                  // 32*64*4 = 8 KB scratch
    int B = in_sizes[0] / AA;

    tsk_precompute<<<dim3(1), dim3(512), 0, stream>>>(W, C, P);
    tsk_main<<<dim3((B + SPB - 1) / SPB), dim3(BLOCK), 0, stream>>>(x, P, out, B);
}